// Round 11
// baseline (258.113 us; speedup 1.0000x reference)
//
#include <hip/hip_runtime.h>

#define EPSF 1e-6f

// dims (fixed for this problem)
#define NB 8
#define LL 4096
#define NHD 8
#define DD 64
#define ROWSTR 512            // H*D
#define NSTR (LL * ROWSTR)    // per-batch stride = 2097152

// workspace float offsets
#define OFF_QSUM 0
#define OFF_KSUM 4096
#define OFF_QNSUM 8192
#define OFF_KNSUM 12288
#define OFF_Z 16384           // 64 floats (atomicAdd target, inside zeroed span)
#define OFF_KV 16448          // 64 nh x 4096 ushort bf16 kv^T (512 KB)
#define OFF_KVP (OFF_KV + 262144)     // 278592: 64 nh x 16 chunks x 4096 partials
#define KVP_FLOATS (64 * 16 * 4096)   // 4194304

typedef __attribute__((ext_vector_type(8))) short short8v;  // 8 bf16 (4 VGPRs)
typedef __attribute__((ext_vector_type(4))) float f32x4;

__device__ __forceinline__ float sigf(float x) {
  return 1.0f / (1.0f + __expf(-x));
}

__device__ __forceinline__ float rsum16(float p) {
  p += __shfl_xor(p, 1, 16);
  p += __shfl_xor(p, 2, 16);
  p += __shfl_xor(p, 4, 16);
  p += __shfl_xor(p, 8, 16);
  return p;
}

__device__ __forceinline__ float rsum8(float p) {
  p += __shfl_xor(p, 1, 8);
  p += __shfl_xor(p, 2, 8);
  p += __shfl_xor(p, 4, 8);
  return p;
}

__device__ __forceinline__ unsigned short b16rne(float x) {
  unsigned int u = __float_as_uint(x);
  return (unsigned short)((u + 0x7FFFu + ((u >> 16) & 1u)) >> 16);
}

__device__ __forceinline__ unsigned int pack2(float a, float b) {
  return (unsigned int)b16rne(a) | ((unsigned int)b16rne(b) << 16);
}

// ---------------- P1: ksum = sum_s sig(k) ----------------
// 2048 blocks x 16 rows (32 KB contiguous each); thread owns fixed col quad.
__global__ __launch_bounds__(256) void k_ksum(const float* __restrict__ k,
                                              float* __restrict__ ws) {
  int bid = blockIdx.x;  // 2048
  int n = bid >> 8, chunk = bid & 255;
  int t = threadIdx.x;
  const float* base = k + (size_t)n * NSTR + (size_t)chunk * 16 * ROWSTR + t * 4;
  float4 acc = make_float4(0.f, 0.f, 0.f, 0.f);
#pragma unroll
  for (int it = 0; it < 8; ++it) {
    const float4 x = *(const float4*)(base + (size_t)it * 1024);
    acc.x += sigf(x.x); acc.y += sigf(x.y); acc.z += sigf(x.z); acc.w += sigf(x.w);
  }
  __shared__ float red[512];
  if (t < 128) {
    red[t * 4 + 0] = acc.x; red[t * 4 + 1] = acc.y;
    red[t * 4 + 2] = acc.z; red[t * 4 + 3] = acc.w;
  }
  __syncthreads();
  if (t >= 128) {
    int c = (t - 128) * 4;
    red[c + 0] += acc.x; red[c + 1] += acc.y;
    red[c + 2] += acc.z; red[c + 3] += acc.w;
  }
  __syncthreads();
  if (t < 128) {
    float* dp = ws + OFF_KSUM + n * 512 + t * 4;
    atomicAdd(dp + 0, red[t * 4 + 0]); atomicAdd(dp + 1, red[t * 4 + 1]);
    atomicAdd(dp + 2, red[t * 4 + 2]); atomicAdd(dp + 3, red[t * 4 + 3]);
  }
}

// ---------------- P2: fused q-pass: qsum AND qn_sum ----------------
__global__ __launch_bounds__(256) void k_qpass(const float* __restrict__ q,
                                               float* __restrict__ ws) {
  int bid = blockIdx.x;  // 2048
  int n = bid >> 8, chunk = bid & 255;
  int t = threadIdx.x;
  int col = (t * 4) & 511;
  __shared__ float vec[512];
  if (t < 128) {
    const float* kp = ws + OFF_KSUM + n * 512 + t * 4;
    vec[t * 4 + 0] = kp[0] + EPSF; vec[t * 4 + 1] = kp[1] + EPSF;
    vec[t * 4 + 2] = kp[2] + EPSF; vec[t * 4 + 3] = kp[3] + EPSF;
  }
  __syncthreads();
  const float4 ve = *(const float4*)&vec[col];
  const float* base = q + (size_t)n * NSTR + (size_t)chunk * 16 * ROWSTR + t * 4;
  float4 qacc = make_float4(0.f, 0.f, 0.f, 0.f);
  float4 nacc = make_float4(0.f, 0.f, 0.f, 0.f);
#pragma unroll
  for (int it = 0; it < 8; ++it) {
    const float4 x = *(const float4*)(base + (size_t)it * 1024);
    float4 s;
    s.x = sigf(x.x); s.y = sigf(x.y); s.z = sigf(x.z); s.w = sigf(x.w);
    qacc.x += s.x; qacc.y += s.y; qacc.z += s.z; qacc.w += s.w;
    float p = (s.x + EPSF) * ve.x + (s.y + EPSF) * ve.y +
              (s.z + EPSF) * ve.z + (s.w + EPSF) * ve.w;
    p = rsum16(p);
    float nrm = 1.0f / p;
    nacc.x += s.x * nrm; nacc.y += s.y * nrm; nacc.z += s.z * nrm; nacc.w += s.w * nrm;
  }
  __shared__ float red[512];
  if (t < 128) {
    red[t * 4 + 0] = qacc.x; red[t * 4 + 1] = qacc.y;
    red[t * 4 + 2] = qacc.z; red[t * 4 + 3] = qacc.w;
  }
  __syncthreads();
  if (t >= 128) {
    int c = (t - 128) * 4;
    red[c + 0] += qacc.x; red[c + 1] += qacc.y;
    red[c + 2] += qacc.z; red[c + 3] += qacc.w;
  }
  __syncthreads();
  if (t < 128) {
    float* dp = ws + OFF_QSUM + n * 512 + t * 4;
    atomicAdd(dp + 0, red[t * 4 + 0]); atomicAdd(dp + 1, red[t * 4 + 1]);
    atomicAdd(dp + 2, red[t * 4 + 2]); atomicAdd(dp + 3, red[t * 4 + 3]);
  }
  __syncthreads();
  if (t < 128) {
    red[t * 4 + 0] = nacc.x; red[t * 4 + 1] = nacc.y;
    red[t * 4 + 2] = nacc.z; red[t * 4 + 3] = nacc.w;
  }
  __syncthreads();
  if (t >= 128) {
    int c = (t - 128) * 4;
    red[c + 0] += nacc.x; red[c + 1] += nacc.y;
    red[c + 2] += nacc.z; red[c + 3] += nacc.w;
  }
  __syncthreads();
  if (t < 128) {
    float* dp = ws + OFF_QNSUM + n * 512 + t * 4;
    atomicAdd(dp + 0, red[t * 4 + 0]); atomicAdd(dp + 1, red[t * 4 + 1]);
    atomicAdd(dp + 2, red[t * 4 + 2]); atomicAdd(dp + 3, red[t * 4 + 3]);
  }
}

// ---------------- P3: kv = khat^T v via MFMA, single bf16 (ncraw + kn_sum fused) ----------------
__global__ __launch_bounds__(512, 4) void k_kv(const float* __restrict__ k,
                                               const float* __restrict__ v,
                                               float* __restrict__ ws) {
  const int bid = blockIdx.x;  // 1024
  const int nh = bid >> 4, chunk = bid & 15;
  const int n = nh >> 3, h = nh & 7;
  const int t = threadIdx.x;

  __shared__ unsigned short kt[64][72];
  __shared__ unsigned short vt[64][72];
  __shared__ float zred[512];
  __shared__ float knred[8][64];

  const float* kbase = k + (size_t)n * NSTR + h * DD;
  const float* vbase = v + (size_t)n * NSTR + h * DD;

  const int srow_l = t >> 3;       // 0..63
  const int tq = t & 7;            // 0..7
  const int c0 = tq * 4, c1 = 32 + tq * 4;
  const int s0 = chunk * 256;

  const float* qnp = ws + OFF_QNSUM + nh * 64;
  float4 qa = *(const float4*)(qnp + c0);
  float4 qb = *(const float4*)(qnp + c1);
  qa.x += EPSF; qa.y += EPSF; qa.z += EPSF; qa.w += EPSF;
  qb.x += EPSF; qb.y += EPSF; qb.z += EPSF; qb.w += EPSF;
  const float* qsp = ws + OFF_QSUM + nh * 64;
  float4 sa = *(const float4*)(qsp + c0);
  float4 sb = *(const float4*)(qsp + c1);
  sa.x += EPSF; sa.y += EPSF; sa.z += EPSF; sa.w += EPSF;
  sb.x += EPSF; sb.y += EPSF; sb.z += EPSF; sb.w += EPSF;

  const int w = t >> 6, lane = t & 63;
  const int dblk = w >> 1, ep = w & 1;
  const int m = lane & 15, grp = lane >> 4;
  const int arow = 16 * dblk + m;
  const int brow0 = 16 * (2 * ep) + m;
  const int brow1 = 16 * (2 * ep + 1) + m;

  f32x4 acc0 = {0.f, 0.f, 0.f, 0.f};
  f32x4 acc1 = {0.f, 0.f, 0.f, 0.f};
  float zloc = 0.f;
  float knacc[8];
#pragma unroll
  for (int i = 0; i < 8; ++i) knacc[i] = 0.f;

  const float* krow = kbase + (size_t)(s0 + srow_l) * ROWSTR;
  const float* vrow = vbase + (size_t)(s0 + srow_l) * ROWSTR;
  float4 kA = *(const float4*)(krow + c0);
  float4 kB = *(const float4*)(krow + c1);
  float4 vA = *(const float4*)(vrow + c0);
  float4 vB = *(const float4*)(vrow + c1);

  for (int sub = 0; sub < 4; ++sub) {
    float4 kAn, kBn, vAn, vBn;
    if (sub < 3) {
      const float* krn = kbase + (size_t)(s0 + (sub + 1) * 64 + srow_l) * ROWSTR;
      const float* vrn = vbase + (size_t)(s0 + (sub + 1) * 64 + srow_l) * ROWSTR;
      kAn = *(const float4*)(krn + c0);
      kBn = *(const float4*)(krn + c1);
      vAn = *(const float4*)(vrn + c0);
      vBn = *(const float4*)(vrn + c1);
    }
    float sk[8];
    sk[0] = sigf(kA.x); sk[1] = sigf(kA.y); sk[2] = sigf(kA.z); sk[3] = sigf(kA.w);
    sk[4] = sigf(kB.x); sk[5] = sigf(kB.y); sk[6] = sigf(kB.z); sk[7] = sigf(kB.w);
    float p = (sk[0] + EPSF) * qa.x + (sk[1] + EPSF) * qa.y +
              (sk[2] + EPSF) * qa.z + (sk[3] + EPSF) * qa.w +
              (sk[4] + EPSF) * qb.x + (sk[5] + EPSF) * qb.y +
              (sk[6] + EPSF) * qb.z + (sk[7] + EPSF) * qb.w;
    float p2 = (sk[0] + EPSF) * sa.x + (sk[1] + EPSF) * sa.y +
               (sk[2] + EPSF) * sa.z + (sk[3] + EPSF) * sa.w +
               (sk[4] + EPSF) * sb.x + (sk[5] + EPSF) * sb.y +
               (sk[6] + EPSF) * sb.z + (sk[7] + EPSF) * sb.w;
    p = rsum8(p);
    p2 = rsum8(p2);
    float wgt = __expf(p);
    if (tq == 0) zloc += wgt;
    float inv2 = 1.0f / p2;
#pragma unroll
    for (int i = 0; i < 8; ++i) knacc[i] += sk[i] * inv2;
    float vv[8] = {vA.x, vA.y, vA.z, vA.w, vB.x, vB.y, vB.z, vB.w};
#pragma unroll
    for (int i = 0; i < 8; ++i) {
      int d = (i < 4) ? (c0 + i) : (c1 + i - 4);
      kt[d][srow_l] = b16rne(sk[i] * wgt);
      vt[d][srow_l] = b16rne(vv[i]);
    }
    __syncthreads();
#pragma unroll
    for (int ks = 0; ks < 2; ++ks) {
      const int sb2 = ks * 32 + 8 * grp;
      short8v A  = *(const short8v*)&kt[arow][sb2];
      short8v B0 = *(const short8v*)&vt[brow0][sb2];
      short8v B1 = *(const short8v*)&vt[brow1][sb2];
      acc0 = __builtin_amdgcn_mfma_f32_16x16x32_bf16(A, B0, acc0, 0, 0, 0);
      acc1 = __builtin_amdgcn_mfma_f32_16x16x32_bf16(A, B1, acc1, 0, 0, 0);
    }
    __syncthreads();
    kA = kAn; kB = kBn; vA = vAn; vB = vBn;
  }

  float* dst = ws + OFF_KVP + (size_t)bid * 4096;
  const int drow = 16 * dblk + 4 * grp;
#pragma unroll
  for (int r = 0; r < 4; ++r) {
    dst[(drow + r) * 64 + brow0] = acc0[r];
    dst[(drow + r) * 64 + brow1] = acc1[r];
  }

#pragma unroll
  for (int i = 0; i < 8; ++i) {
    knacc[i] += __shfl_xor(knacc[i], 8, 64);
    knacc[i] += __shfl_xor(knacc[i], 16, 64);
    knacc[i] += __shfl_xor(knacc[i], 32, 64);
  }
  if (lane < 8) {
#pragma unroll
    for (int i = 0; i < 4; ++i) {
      knred[w][lane * 4 + i] = knacc[i];
      knred[w][32 + lane * 4 + i] = knacc[4 + i];
    }
  }
  zred[t] = zloc;
  __syncthreads();
  if (t < 64) {
    float s = 0.f;
#pragma unroll
    for (int ww = 0; ww < 8; ++ww) s += knred[ww][t];
    atomicAdd(&ws[OFF_KNSUM + nh * 64 + t], s);
  }
  for (int s = 256; s >= 1; s >>= 1) {
    if (t < s) zred[t] += zred[t + s];
    __syncthreads();
  }
  if (t == 0) atomicAdd(&ws[OFF_Z + nh], zred[0]);
}

// ---------------- P4: reduce 16 partials, apply S/Z, transpose, emit bf16 kv^T ----------------
__global__ __launch_bounds__(256) void k_kvred(float* __restrict__ ws) {
  int nh = blockIdx.x;  // 64
  int t = threadIdx.x;
  float scale = (float)LL / ws[OFF_Z + nh];
  __shared__ float lds[64][69];
  const float4* src = (const float4*)(ws + OFF_KVP);
#pragma unroll
  for (int i = 0; i < 4; ++i) {
    int off = i * 256 + t;  // float4 index 0..1023 within nh ([d][e] layout)
    float4 s = make_float4(0.f, 0.f, 0.f, 0.f);
#pragma unroll
    for (int c = 0; c < 16; ++c) {
      float4 x = src[(size_t)((nh * 16 + c) << 10) + off];
      s.x += x.x; s.y += x.y; s.z += x.z; s.w += x.w;
    }
    int d = off >> 4, e0 = (off & 15) * 4;
    lds[d][e0 + 0] = s.x * scale; lds[d][e0 + 1] = s.y * scale;
    lds[d][e0 + 2] = s.z * scale; lds[d][e0 + 3] = s.w * scale;
  }
  __syncthreads();
  int e = t >> 2, d0 = (t & 3) * 16;
  unsigned int words[8];
#pragma unroll
  for (int j = 0; j < 8; ++j)
    words[j] = pack2(lds[d0 + 2 * j][e], lds[d0 + 2 * j + 1][e]);
  unsigned int* dstp = (unsigned int*)((unsigned short*)(ws + OFF_KV) + (size_t)nh * 4096 + e * 64 + d0);
#pragma unroll
  for (int j = 0; j < 8; ++j) dstp[j] = words[j];
}

// ---------------- P5: out = (sig(q) . kv) * scl via MFMA ----------------
__global__ __launch_bounds__(256) void k_out(const float* __restrict__ q,
                                             float* __restrict__ out,
                                             const float* __restrict__ ws) {
  int bid = blockIdx.x;  // 2048
  int nh = bid >> 5, chunk = bid & 31;
  int n = nh >> 3, h = nh & 7;
  int t = threadIdx.x, tq = t & 15, g = t >> 4;
  __shared__ unsigned short sqb[128][72];   // bf16 sig(q), rows l
  __shared__ unsigned short kvb[64][72];    // bf16 kv^T, rows e
  __shared__ float scl[128];
  __shared__ float ksv[64], knv[64];
  if (t < 64) {
    ksv[t] = ws[OFF_KSUM + nh * 64 + t] + EPSF;
    knv[t] = ws[OFF_KNSUM + nh * 64 + t] + EPSF;
  }
  {
    int r0 = t >> 2, c0 = (t & 3) * 16;
    const short8v* gsrc = (const short8v*)((const unsigned short*)(ws + OFF_KV) +
                                           (size_t)nh * 4096 + r0 * 64 + c0);
    short8v a = gsrc[0], b = gsrc[1];
    *(short8v*)&kvb[r0][c0] = a;
    *(short8v*)&kvb[r0][c0 + 8] = b;
  }
  __syncthreads();
  const float4 ke = *(const float4*)&ksv[tq * 4];
  const float4 kne = *(const float4*)&knv[tq * 4];
  const float* qbase = q + (size_t)n * NSTR + h * DD + tq * 4;
  int l0 = chunk * 128;
#pragma unroll
  for (int rr = 0; rr < 8; ++rr) {
    int row = g + rr * 16;
    const float4 x = *(const float4*)(qbase + (size_t)(l0 + row) * ROWSTR);
    float4 s;
    s.x = sigf(x.x); s.y = sigf(x.y); s.z = sigf(x.z); s.w = sigf(x.w);
    *(unsigned int*)&sqb[row][tq * 4] = pack2(s.x, s.y);
    *(unsigned int*)&sqb[row][tq * 4 + 2] = pack2(s.z, s.w);
    float p1 = (s.x + EPSF) * ke.x + (s.y + EPSF) * ke.y +
               (s.z + EPSF) * ke.z + (s.w + EPSF) * ke.w;
    float p2 = (s.x + EPSF) * kne.x + (s.y + EPSF) * kne.y +
               (s.z + EPSF) * kne.z + (s.w + EPSF) * kne.w;
    p1 = rsum16(p1);
    p2 = rsum16(p2);
    if (tq == 0) scl[row] = (1.0f / p1) * sigf(p2);  // L/S == 1
  }
  __syncthreads();
  int w = t >> 6, lane = t & 63;
  int m = lane & 15, grp = lane >> 4;
  f32x4 a00 = {0,0,0,0}, a01 = {0,0,0,0}, a02 = {0,0,0,0}, a03 = {0,0,0,0};
  f32x4 a10 = {0,0,0,0}, a11 = {0,0,0,0}, a12 = {0,0,0,0}, a13 = {0,0,0,0};
#pragma unroll
  for (int ks = 0; ks < 2; ++ks) {
    const int sb = ks * 32 + 8 * grp;
    short8v A0 = *(const short8v*)&sqb[(2 * w + 0) * 16 + m][sb];
    short8v A1 = *(const short8v*)&sqb[(2 * w + 1) * 16 + m][sb];
    short8v B0 = *(const short8v*)&kvb[0 * 16 + m][sb];
    short8v B1 = *(const short8v*)&kvb[1 * 16 + m][sb];
    short8v B2 = *(const short8v*)&kvb[2 * 16 + m][sb];
    short8v B3 = *(const short8v*)&kvb[3 * 16 + m][sb];
    a00 = __builtin_amdgcn_mfma_f32_16x16x32_bf16(A0, B0, a00, 0, 0, 0);
    a01 = __builtin_amdgcn_mfma_f32_16x16x32_bf16(A0, B1, a01, 0, 0, 0);
    a02 = __builtin_amdgcn_mfma_f32_16x16x32_bf16(A0, B2, a02, 0, 0, 0);
    a03 = __builtin_amdgcn_mfma_f32_16x16x32_bf16(A0, B3, a03, 0, 0, 0);
    a10 = __builtin_amdgcn_mfma_f32_16x16x32_bf16(A1, B0, a10, 0, 0, 0);
    a11 = __builtin_amdgcn_mfma_f32_16x16x32_bf16(A1, B1, a11, 0, 0, 0);
    a12 = __builtin_amdgcn_mfma_f32_16x16x32_bf16(A1, B2, a12, 0, 0, 0);
    a13 = __builtin_amdgcn_mfma_f32_16x16x32_bf16(A1, B3, a13, 0, 0, 0);
  }
  float* obase = out + (size_t)n * NSTR + h * DD;
#pragma unroll
  for (int mt = 0; mt < 2; ++mt) {
    int lrow = (2 * w + mt) * 16 + 4 * grp;
#pragma unroll
    for (int r = 0; r < 4; ++r) {
      float sc = scl[lrow + r];
      float* orow = obase + (size_t)(l0 + lrow + r) * ROWSTR;
      if (mt == 0) {
        orow[0 * 16 + m] = a00[r] * sc; orow[1 * 16 + m] = a01[r] * sc;
        orow[2 * 16 + m] = a02[r] * sc; orow[3 * 16 + m] = a03[r] * sc;
      } else {
        orow[0 * 16 + m] = a10[r] * sc; orow[1 * 16 + m] = a11[r] * sc;
        orow[2 * 16 + m] = a12[r] * sc; orow[3 * 16 + m] = a13[r] * sc;
      }
    }
  }
}

extern "C" void kernel_launch(void* const* d_in, const int* in_sizes, int n_in,
                              void* d_out, int out_size, void* d_ws, size_t ws_size,
                              hipStream_t stream) {
  const float* q = (const float*)d_in[0];
  const float* k = (const float*)d_in[1];
  const float* v = (const float*)d_in[2];
  float* out = (float*)d_out;
  float* ws = (float*)d_ws;

  // zero accumulators: sums + Z  (kv^T/kvp fully overwritten each launch)
  hipMemsetAsync(d_ws, 0, (size_t)OFF_KV * sizeof(float), stream);

  hipLaunchKernelGGL(k_ksum, dim3(2048), dim3(256), 0, stream, k, ws);
  hipLaunchKernelGGL(k_qpass, dim3(2048), dim3(256), 0, stream, q, ws);
  hipLaunchKernelGGL(k_kv, dim3(1024), dim3(512), 0, stream, k, v, ws);
  hipLaunchKernelGGL(k_kvred, dim3(64), dim3(256), 0, stream, ws);
  hipLaunchKernelGGL(k_out, dim3(2048), dim3(256), 0, stream, q, out, ws);
}

// Round 12
// 112.239 us; speedup vs baseline: 2.2997x; 2.2997x over previous
//
#include <hip/hip_runtime.h>

#define EPSF 1e-6f

// dims (fixed for this problem)
#define NB 8
#define LL 4096
#define NHD 8
#define DD 64
#define ROWSTR 512            // H*D
#define NSTR (LL * ROWSTR)    // per-batch stride = 2097152

// workspace float offsets
#define OFF_QSUM 0
#define OFF_KSUM 4096
#define OFF_QNSUM 8192
#define OFF_KNSUM 12288
#define OFF_Z 16384           // 64 floats (atomicAdd target, inside zeroed span)
#define OFF_KV 16448          // 64 nh x 4096 ushort bf16 kv^T (512 KB)
#define OFF_KVP (OFF_KV + 262144)     // 278592: 64 nh x 16 chunks x 4096 partials
#define KVP_FLOATS (64 * 16 * 4096)   // 4194304
// stage-1 partial buffers ALIAS the KVP region (consumed before k_kv writes it)
#define OFF_KP1 OFF_KVP               // 2048 x 512
#define OFF_QP1 (OFF_KVP + 1048576)   // 2048 x 512
#define OFF_QNP1 (OFF_KVP + 2097152)  // 2048 x 512

typedef __attribute__((ext_vector_type(8))) short short8v;  // 8 bf16 (4 VGPRs)
typedef __attribute__((ext_vector_type(4))) float f32x4;

__device__ __forceinline__ float sigf(float x) {
  return 1.0f / (1.0f + __expf(-x));
}

__device__ __forceinline__ float rsum16(float p) {
  p += __shfl_xor(p, 1, 16);
  p += __shfl_xor(p, 2, 16);
  p += __shfl_xor(p, 4, 16);
  p += __shfl_xor(p, 8, 16);
  return p;
}

__device__ __forceinline__ float rsum8(float p) {
  p += __shfl_xor(p, 1, 8);
  p += __shfl_xor(p, 2, 8);
  p += __shfl_xor(p, 4, 8);
  return p;
}

__device__ __forceinline__ unsigned short b16rne(float x) {
  unsigned int u = __float_as_uint(x);
  return (unsigned short)((u + 0x7FFFu + ((u >> 16) & 1u)) >> 16);
}

__device__ __forceinline__ unsigned int pack2(float a, float b) {
  return (unsigned int)b16rne(a) | ((unsigned int)b16rne(b) << 16);
}

// ---------------- P1: ksum partials (no atomics) ----------------
__global__ __launch_bounds__(256) void k_ksum(const float* __restrict__ k,
                                              float* __restrict__ ws) {
  int bid = blockIdx.x;  // 2048
  int n = bid >> 8, chunk = bid & 255;
  int t = threadIdx.x;
  const float* base = k + (size_t)n * NSTR + (size_t)chunk * 16 * ROWSTR + t * 4;
  float4 acc = make_float4(0.f, 0.f, 0.f, 0.f);
#pragma unroll
  for (int it = 0; it < 8; ++it) {
    const float4 x = *(const float4*)(base + (size_t)it * 1024);
    acc.x += sigf(x.x); acc.y += sigf(x.y); acc.z += sigf(x.z); acc.w += sigf(x.w);
  }
  __shared__ float red[512];
  if (t < 128) {
    red[t * 4 + 0] = acc.x; red[t * 4 + 1] = acc.y;
    red[t * 4 + 2] = acc.z; red[t * 4 + 3] = acc.w;
  }
  __syncthreads();
  if (t >= 128) {
    int c = (t - 128) * 4;
    red[c + 0] += acc.x; red[c + 1] += acc.y;
    red[c + 2] += acc.z; red[c + 3] += acc.w;
  }
  __syncthreads();
  if (t < 128)
    *(float4*)(ws + OFF_KP1 + (size_t)bid * 512 + t * 4) = *(float4*)&red[t * 4];
}

// ---------------- R1: reduce 256 chunk-partials per (n,col) ----------------
__global__ __launch_bounds__(256) void k_red1(const float* __restrict__ src,
                                              float* __restrict__ dst) {
  int bid = blockIdx.x;  // 64: n = bid>>3, colgroup = bid&7
  int n = bid >> 3, cg = bid & 7;
  int t = threadIdx.x;
  int col = cg * 64 + (t & 63);
  int ci = t >> 6;  // 0..3
  const float* base = src + (size_t)n * 256 * 512 + col;
  float s = 0.f;
#pragma unroll 8
  for (int c = 0; c < 64; ++c) s += base[(size_t)(ci * 64 + c) * 512];
  __shared__ float red[4][64];
  red[ci][t & 63] = s;
  __syncthreads();
  if (t < 64)
    dst[n * 512 + cg * 64 + t] = red[0][t] + red[1][t] + red[2][t] + red[3][t];
}

// ---------------- P2: fused q-pass partials: qsum AND qn_sum ----------------
__global__ __launch_bounds__(256) void k_qpass(const float* __restrict__ q,
                                               float* __restrict__ ws) {
  int bid = blockIdx.x;  // 2048
  int n = bid >> 8, chunk = bid & 255;
  int t = threadIdx.x;
  int col = (t * 4) & 511;
  __shared__ float vec[512];
  if (t < 128) {
    const float* kp = ws + OFF_KSUM + n * 512 + t * 4;
    vec[t * 4 + 0] = kp[0] + EPSF; vec[t * 4 + 1] = kp[1] + EPSF;
    vec[t * 4 + 2] = kp[2] + EPSF; vec[t * 4 + 3] = kp[3] + EPSF;
  }
  __syncthreads();
  const float4 ve = *(const float4*)&vec[col];
  const float* base = q + (size_t)n * NSTR + (size_t)chunk * 16 * ROWSTR + t * 4;
  float4 qacc = make_float4(0.f, 0.f, 0.f, 0.f);
  float4 nacc = make_float4(0.f, 0.f, 0.f, 0.f);
#pragma unroll
  for (int it = 0; it < 8; ++it) {
    const float4 x = *(const float4*)(base + (size_t)it * 1024);
    float4 s;
    s.x = sigf(x.x); s.y = sigf(x.y); s.z = sigf(x.z); s.w = sigf(x.w);
    qacc.x += s.x; qacc.y += s.y; qacc.z += s.z; qacc.w += s.w;
    float p = (s.x + EPSF) * ve.x + (s.y + EPSF) * ve.y +
              (s.z + EPSF) * ve.z + (s.w + EPSF) * ve.w;
    p = rsum16(p);
    float nrm = 1.0f / p;
    nacc.x += s.x * nrm; nacc.y += s.y * nrm; nacc.z += s.z * nrm; nacc.w += s.w * nrm;
  }
  __shared__ float red[512];
  if (t < 128) {
    red[t * 4 + 0] = qacc.x; red[t * 4 + 1] = qacc.y;
    red[t * 4 + 2] = qacc.z; red[t * 4 + 3] = qacc.w;
  }
  __syncthreads();
  if (t >= 128) {
    int c = (t - 128) * 4;
    red[c + 0] += qacc.x; red[c + 1] += qacc.y;
    red[c + 2] += qacc.z; red[c + 3] += qacc.w;
  }
  __syncthreads();
  if (t < 128)
    *(float4*)(ws + OFF_QP1 + (size_t)bid * 512 + t * 4) = *(float4*)&red[t * 4];
  __syncthreads();
  if (t < 128) {
    red[t * 4 + 0] = nacc.x; red[t * 4 + 1] = nacc.y;
    red[t * 4 + 2] = nacc.z; red[t * 4 + 3] = nacc.w;
  }
  __syncthreads();
  if (t >= 128) {
    int c = (t - 128) * 4;
    red[c + 0] += nacc.x; red[c + 1] += nacc.y;
    red[c + 2] += nacc.z; red[c + 3] += nacc.w;
  }
  __syncthreads();
  if (t < 128)
    *(float4*)(ws + OFF_QNP1 + (size_t)bid * 512 + t * 4) = *(float4*)&red[t * 4];
}

// ---------------- R2: reduce both q partial arrays ----------------
__global__ __launch_bounds__(256) void k_redq(float* __restrict__ ws) {
  int bid = blockIdx.x;  // 128: first 64 -> qsum, next 64 -> qn_sum
  int which = bid >> 6, id = bid & 63;
  const float* src = ws + (which ? OFF_QNP1 : OFF_QP1);
  float* dst = ws + (which ? OFF_QNSUM : OFF_QSUM);
  int n = id >> 3, cg = id & 7;
  int t = threadIdx.x;
  int col = cg * 64 + (t & 63);
  int ci = t >> 6;
  const float* base = src + (size_t)n * 256 * 512 + col;
  float s = 0.f;
#pragma unroll 8
  for (int c = 0; c < 64; ++c) s += base[(size_t)(ci * 64 + c) * 512];
  __shared__ float red[4][64];
  red[ci][t & 63] = s;
  __syncthreads();
  if (t < 64)
    dst[n * 512 + cg * 64 + t] = red[0][t] + red[1][t] + red[2][t] + red[3][t];
}

// ---------------- P3: kv = khat^T v via MFMA, single bf16 (ncraw + kn_sum fused) ----------------
__global__ __launch_bounds__(512, 4) void k_kv(const float* __restrict__ k,
                                               const float* __restrict__ v,
                                               float* __restrict__ ws) {
  const int bid = blockIdx.x;  // 1024
  const int nh = bid >> 4, chunk = bid & 15;
  const int n = nh >> 3, h = nh & 7;
  const int t = threadIdx.x;

  __shared__ unsigned short kt[64][72];
  __shared__ unsigned short vt[64][72];
  __shared__ float zred[512];
  __shared__ float knred[8][64];

  const float* kbase = k + (size_t)n * NSTR + h * DD;
  const float* vbase = v + (size_t)n * NSTR + h * DD;

  const int srow_l = t >> 3;
  const int tq = t & 7;
  const int c0 = tq * 4, c1 = 32 + tq * 4;
  const int s0 = chunk * 256;

  const float* qnp = ws + OFF_QNSUM + nh * 64;
  float4 qa = *(const float4*)(qnp + c0);
  float4 qb = *(const float4*)(qnp + c1);
  qa.x += EPSF; qa.y += EPSF; qa.z += EPSF; qa.w += EPSF;
  qb.x += EPSF; qb.y += EPSF; qb.z += EPSF; qb.w += EPSF;
  const float* qsp = ws + OFF_QSUM + nh * 64;
  float4 sa = *(const float4*)(qsp + c0);
  float4 sb = *(const float4*)(qsp + c1);
  sa.x += EPSF; sa.y += EPSF; sa.z += EPSF; sa.w += EPSF;
  sb.x += EPSF; sb.y += EPSF; sb.z += EPSF; sb.w += EPSF;

  const int w = t >> 6, lane = t & 63;
  const int dblk = w >> 1, ep = w & 1;
  const int m = lane & 15, grp = lane >> 4;
  const int arow = 16 * dblk + m;
  const int brow0 = 16 * (2 * ep) + m;
  const int brow1 = 16 * (2 * ep + 1) + m;

  f32x4 acc0 = {0.f, 0.f, 0.f, 0.f};
  f32x4 acc1 = {0.f, 0.f, 0.f, 0.f};
  float zloc = 0.f;
  float knacc[8];
#pragma unroll
  for (int i = 0; i < 8; ++i) knacc[i] = 0.f;

  const float* krow = kbase + (size_t)(s0 + srow_l) * ROWSTR;
  const float* vrow = vbase + (size_t)(s0 + srow_l) * ROWSTR;
  float4 kA = *(const float4*)(krow + c0);
  float4 kB = *(const float4*)(krow + c1);
  float4 vA = *(const float4*)(vrow + c0);
  float4 vB = *(const float4*)(vrow + c1);

  for (int sub = 0; sub < 4; ++sub) {
    float4 kAn, kBn, vAn, vBn;
    if (sub < 3) {
      const float* krn = kbase + (size_t)(s0 + (sub + 1) * 64 + srow_l) * ROWSTR;
      const float* vrn = vbase + (size_t)(s0 + (sub + 1) * 64 + srow_l) * ROWSTR;
      kAn = *(const float4*)(krn + c0);
      kBn = *(const float4*)(krn + c1);
      vAn = *(const float4*)(vrn + c0);
      vBn = *(const float4*)(vrn + c1);
    }
    float sk[8];
    sk[0] = sigf(kA.x); sk[1] = sigf(kA.y); sk[2] = sigf(kA.z); sk[3] = sigf(kA.w);
    sk[4] = sigf(kB.x); sk[5] = sigf(kB.y); sk[6] = sigf(kB.z); sk[7] = sigf(kB.w);
    float p = (sk[0] + EPSF) * qa.x + (sk[1] + EPSF) * qa.y +
              (sk[2] + EPSF) * qa.z + (sk[3] + EPSF) * qa.w +
              (sk[4] + EPSF) * qb.x + (sk[5] + EPSF) * qb.y +
              (sk[6] + EPSF) * qb.z + (sk[7] + EPSF) * qb.w;
    float p2 = (sk[0] + EPSF) * sa.x + (sk[1] + EPSF) * sa.y +
               (sk[2] + EPSF) * sa.z + (sk[3] + EPSF) * sa.w +
               (sk[4] + EPSF) * sb.x + (sk[5] + EPSF) * sb.y +
               (sk[6] + EPSF) * sb.z + (sk[7] + EPSF) * sb.w;
    p = rsum8(p);
    p2 = rsum8(p2);
    float wgt = __expf(p);
    if (tq == 0) zloc += wgt;
    float inv2 = 1.0f / p2;
#pragma unroll
    for (int i = 0; i < 8; ++i) knacc[i] += sk[i] * inv2;
    float vv[8] = {vA.x, vA.y, vA.z, vA.w, vB.x, vB.y, vB.z, vB.w};
#pragma unroll
    for (int i = 0; i < 8; ++i) {
      int d = (i < 4) ? (c0 + i) : (c1 + i - 4);
      kt[d][srow_l] = b16rne(sk[i] * wgt);
      vt[d][srow_l] = b16rne(vv[i]);
    }
    __syncthreads();
#pragma unroll
    for (int ks = 0; ks < 2; ++ks) {
      const int sb2 = ks * 32 + 8 * grp;
      short8v A  = *(const short8v*)&kt[arow][sb2];
      short8v B0 = *(const short8v*)&vt[brow0][sb2];
      short8v B1 = *(const short8v*)&vt[brow1][sb2];
      acc0 = __builtin_amdgcn_mfma_f32_16x16x32_bf16(A, B0, acc0, 0, 0, 0);
      acc1 = __builtin_amdgcn_mfma_f32_16x16x32_bf16(A, B1, acc1, 0, 0, 0);
    }
    __syncthreads();
    kA = kAn; kB = kBn; vA = vAn; vB = vBn;
  }

  float* dst = ws + OFF_KVP + (size_t)bid * 4096;
  const int drow = 16 * dblk + 4 * grp;
#pragma unroll
  for (int r = 0; r < 4; ++r) {
    dst[(drow + r) * 64 + brow0] = acc0[r];
    dst[(drow + r) * 64 + brow1] = acc1[r];
  }

#pragma unroll
  for (int i = 0; i < 8; ++i) {
    knacc[i] += __shfl_xor(knacc[i], 8, 64);
    knacc[i] += __shfl_xor(knacc[i], 16, 64);
    knacc[i] += __shfl_xor(knacc[i], 32, 64);
  }
  if (lane < 8) {
#pragma unroll
    for (int i = 0; i < 4; ++i) {
      knred[w][lane * 4 + i] = knacc[i];
      knred[w][32 + lane * 4 + i] = knacc[4 + i];
    }
  }
  zred[t] = zloc;
  __syncthreads();
  if (t < 64) {
    float s = 0.f;
#pragma unroll
    for (int ww = 0; ww < 8; ++ww) s += knred[ww][t];
    atomicAdd(&ws[OFF_KNSUM + nh * 64 + t], s);
  }
  for (int s = 256; s >= 1; s >>= 1) {
    if (t < s) zred[t] += zred[t + s];
    __syncthreads();
  }
  if (t == 0) atomicAdd(&ws[OFF_Z + nh], zred[0]);
}

// ---------------- P4: reduce 16 partials, apply S/Z, transpose, emit bf16 kv^T ----------------
__global__ __launch_bounds__(256) void k_kvred(float* __restrict__ ws) {
  int nh = blockIdx.x;  // 64
  int t = threadIdx.x;
  float scale = (float)LL / ws[OFF_Z + nh];
  __shared__ float lds[64][69];
  const float4* src = (const float4*)(ws + OFF_KVP);
#pragma unroll
  for (int i = 0; i < 4; ++i) {
    int off = i * 256 + t;
    float4 s = make_float4(0.f, 0.f, 0.f, 0.f);
#pragma unroll
    for (int c = 0; c < 16; ++c) {
      float4 x = src[(size_t)((nh * 16 + c) << 10) + off];
      s.x += x.x; s.y += x.y; s.z += x.z; s.w += x.w;
    }
    int d = off >> 4, e0 = (off & 15) * 4;
    lds[d][e0 + 0] = s.x * scale; lds[d][e0 + 1] = s.y * scale;
    lds[d][e0 + 2] = s.z * scale; lds[d][e0 + 3] = s.w * scale;
  }
  __syncthreads();
  int e = t >> 2, d0 = (t & 3) * 16;
  unsigned int words[8];
#pragma unroll
  for (int j = 0; j < 8; ++j)
    words[j] = pack2(lds[d0 + 2 * j][e], lds[d0 + 2 * j + 1][e]);
  unsigned int* dstp = (unsigned int*)((unsigned short*)(ws + OFF_KV) + (size_t)nh * 4096 + e * 64 + d0);
#pragma unroll
  for (int j = 0; j < 8; ++j) dstp[j] = words[j];
}

// ---------------- P5: out = (sig(q) . kv) * scl via MFMA ----------------
__global__ __launch_bounds__(256) void k_out(const float* __restrict__ q,
                                             float* __restrict__ out,
                                             const float* __restrict__ ws) {
  int bid = blockIdx.x;  // 2048
  int nh = bid >> 5, chunk = bid & 31;
  int n = nh >> 3, h = nh & 7;
  int t = threadIdx.x, tq = t & 15, g = t >> 4;
  __shared__ unsigned short sqb[128][72];
  __shared__ unsigned short kvb[64][72];
  __shared__ float scl[128];
  __shared__ float ksv[64], knv[64];
  if (t < 64) {
    ksv[t] = ws[OFF_KSUM + nh * 64 + t] + EPSF;
    knv[t] = ws[OFF_KNSUM + nh * 64 + t] + EPSF;
  }
  {
    int r0 = t >> 2, c0 = (t & 3) * 16;
    const short8v* gsrc = (const short8v*)((const unsigned short*)(ws + OFF_KV) +
                                           (size_t)nh * 4096 + r0 * 64 + c0);
    short8v a = gsrc[0], b = gsrc[1];
    *(short8v*)&kvb[r0][c0] = a;
    *(short8v*)&kvb[r0][c0 + 8] = b;
  }
  __syncthreads();
  const float4 ke = *(const float4*)&ksv[tq * 4];
  const float4 kne = *(const float4*)&knv[tq * 4];
  const float* qbase = q + (size_t)n * NSTR + h * DD + tq * 4;
  int l0 = chunk * 128;
#pragma unroll
  for (int rr = 0; rr < 8; ++rr) {
    int row = g + rr * 16;
    const float4 x = *(const float4*)(qbase + (size_t)(l0 + row) * ROWSTR);
    float4 s;
    s.x = sigf(x.x); s.y = sigf(x.y); s.z = sigf(x.z); s.w = sigf(x.w);
    *(unsigned int*)&sqb[row][tq * 4] = pack2(s.x, s.y);
    *(unsigned int*)&sqb[row][tq * 4 + 2] = pack2(s.z, s.w);
    float p1 = (s.x + EPSF) * ke.x + (s.y + EPSF) * ke.y +
               (s.z + EPSF) * ke.z + (s.w + EPSF) * ke.w;
    float p2 = (s.x + EPSF) * kne.x + (s.y + EPSF) * kne.y +
               (s.z + EPSF) * kne.z + (s.w + EPSF) * kne.w;
    p1 = rsum16(p1);
    p2 = rsum16(p2);
    if (tq == 0) scl[row] = (1.0f / p1) * sigf(p2);  // L/S == 1
  }
  __syncthreads();
  int w = t >> 6, lane = t & 63;
  int m = lane & 15, grp = lane >> 4;
  f32x4 a00 = {0,0,0,0}, a01 = {0,0,0,0}, a02 = {0,0,0,0}, a03 = {0,0,0,0};
  f32x4 a10 = {0,0,0,0}, a11 = {0,0,0,0}, a12 = {0,0,0,0}, a13 = {0,0,0,0};
#pragma unroll
  for (int ks = 0; ks < 2; ++ks) {
    const int sb = ks * 32 + 8 * grp;
    short8v A0 = *(const short8v*)&sqb[(2 * w + 0) * 16 + m][sb];
    short8v A1 = *(const short8v*)&sqb[(2 * w + 1) * 16 + m][sb];
    short8v B0 = *(const short8v*)&kvb[0 * 16 + m][sb];
    short8v B1 = *(const short8v*)&kvb[1 * 16 + m][sb];
    short8v B2 = *(const short8v*)&kvb[2 * 16 + m][sb];
    short8v B3 = *(const short8v*)&kvb[3 * 16 + m][sb];
    a00 = __builtin_amdgcn_mfma_f32_16x16x32_bf16(A0, B0, a00, 0, 0, 0);
    a01 = __builtin_amdgcn_mfma_f32_16x16x32_bf16(A0, B1, a01, 0, 0, 0);
    a02 = __builtin_amdgcn_mfma_f32_16x16x32_bf16(A0, B2, a02, 0, 0, 0);
    a03 = __builtin_amdgcn_mfma_f32_16x16x32_bf16(A0, B3, a03, 0, 0, 0);
    a10 = __builtin_amdgcn_mfma_f32_16x16x32_bf16(A1, B0, a10, 0, 0, 0);
    a11 = __builtin_amdgcn_mfma_f32_16x16x32_bf16(A1, B1, a11, 0, 0, 0);
    a12 = __builtin_amdgcn_mfma_f32_16x16x32_bf16(A1, B2, a12, 0, 0, 0);
    a13 = __builtin_amdgcn_mfma_f32_16x16x32_bf16(A1, B3, a13, 0, 0, 0);
  }
  float* obase = out + (size_t)n * NSTR + h * DD;
#pragma unroll
  for (int mt = 0; mt < 2; ++mt) {
    int lrow = (2 * w + mt) * 16 + 4 * grp;
#pragma unroll
    for (int r = 0; r < 4; ++r) {
      float sc = scl[lrow + r];
      float* orow = obase + (size_t)(l0 + lrow + r) * ROWSTR;
      if (mt == 0) {
        orow[0 * 16 + m] = a00[r] * sc; orow[1 * 16 + m] = a01[r] * sc;
        orow[2 * 16 + m] = a02[r] * sc; orow[3 * 16 + m] = a03[r] * sc;
      } else {
        orow[0 * 16 + m] = a10[r] * sc; orow[1 * 16 + m] = a11[r] * sc;
        orow[2 * 16 + m] = a12[r] * sc; orow[3 * 16 + m] = a13[r] * sc;
      }
    }
  }
}

extern "C" void kernel_launch(void* const* d_in, const int* in_sizes, int n_in,
                              void* d_out, int out_size, void* d_ws, size_t ws_size,
                              hipStream_t stream) {
  const float* q = (const float*)d_in[0];
  const float* k = (const float*)d_in[1];
  const float* v = (const float*)d_in[2];
  float* out = (float*)d_out;
  float* ws = (float*)d_ws;

  // zero small accumulators (kn_sum + Z still atomic; rest fully overwritten)
  hipMemsetAsync(d_ws, 0, (size_t)OFF_KV * sizeof(float), stream);

  hipLaunchKernelGGL(k_ksum, dim3(2048), dim3(256), 0, stream, k, ws);
  hipLaunchKernelGGL(k_red1, dim3(64), dim3(256), 0, stream, ws + OFF_KP1, ws + OFF_KSUM);
  hipLaunchKernelGGL(k_qpass, dim3(2048), dim3(256), 0, stream, q, ws);
  hipLaunchKernelGGL(k_redq, dim3(128), dim3(256), 0, stream, ws);
  hipLaunchKernelGGL(k_kv, dim3(1024), dim3(512), 0, stream, k, v, ws);
  hipLaunchKernelGGL(k_kvred, dim3(64), dim3(256), 0, stream, ws);
  hipLaunchKernelGGL(k_out, dim3(2048), dim3(256), 0, stream, q, out, ws);
}

// Round 13
// 104.558 us; speedup vs baseline: 2.4686x; 1.0735x over previous
//
#include <hip/hip_runtime.h>

#define EPSF 1e-6f

// dims (fixed for this problem)
#define NB 8
#define LL 4096
#define NHD 8
#define DD 64
#define ROWSTR 512            // H*D
#define NSTR (LL * ROWSTR)    // per-batch stride = 2097152

// workspace float offsets — every region fully overwritten each launch (no memset)
#define OFF_QSUM 0
#define OFF_KSUM 4096
#define OFF_QNSUM 8192
#define OFF_KNSUM 12288
#define OFF_KV 16448          // 64 nh x 4096 ushort bf16 kv^T (512 KB)
#define OFF_KVP (OFF_KV + 262144)     // 278592: 64 nh x 16 chunks x 4096 partials
#define KVP_FLOATS (64 * 16 * 4096)   // 4194304
// stage-1 partial buffers ALIAS the KVP region (consumed before k_kv writes it)
#define OFF_KP1 OFF_KVP               // 2048 x 512
#define OFF_QP1 (OFF_KVP + 1048576)   // 2048 x 512
#define OFF_QNP1 (OFF_KVP + 2097152)  // 2048 x 512
// kn / z partials (written by k_kv, reduced by k_kvred)
#define OFF_KNP (OFF_KVP + KVP_FLOATS)        // 1024 x 64
#define OFF_ZP (OFF_KNP + 65536)              // 1024

typedef __attribute__((ext_vector_type(8))) short short8v;  // 8 bf16 (4 VGPRs)
typedef __attribute__((ext_vector_type(4))) float f32x4;

__device__ __forceinline__ float sigf(float x) {
  return 1.0f / (1.0f + __expf(-x));
}

__device__ __forceinline__ float rsum16(float p) {
  p += __shfl_xor(p, 1, 16);
  p += __shfl_xor(p, 2, 16);
  p += __shfl_xor(p, 4, 16);
  p += __shfl_xor(p, 8, 16);
  return p;
}

__device__ __forceinline__ float rsum8(float p) {
  p += __shfl_xor(p, 1, 8);
  p += __shfl_xor(p, 2, 8);
  p += __shfl_xor(p, 4, 8);
  return p;
}

__device__ __forceinline__ unsigned short b16rne(float x) {
  unsigned int u = __float_as_uint(x);
  return (unsigned short)((u + 0x7FFFu + ((u >> 16) & 1u)) >> 16);
}

__device__ __forceinline__ unsigned int pack2(float a, float b) {
  return (unsigned int)b16rne(a) | ((unsigned int)b16rne(b) << 16);
}

// ---------------- P1: ksum partials (no atomics) ----------------
__global__ __launch_bounds__(256) void k_ksum(const float* __restrict__ k,
                                              float* __restrict__ ws) {
  int bid = blockIdx.x;  // 2048
  int n = bid >> 8, chunk = bid & 255;
  int t = threadIdx.x;
  const float* base = k + (size_t)n * NSTR + (size_t)chunk * 16 * ROWSTR + t * 4;
  float4 acc = make_float4(0.f, 0.f, 0.f, 0.f);
#pragma unroll
  for (int it = 0; it < 8; ++it) {
    const float4 x = *(const float4*)(base + (size_t)it * 1024);
    acc.x += sigf(x.x); acc.y += sigf(x.y); acc.z += sigf(x.z); acc.w += sigf(x.w);
  }
  __shared__ float red[512];
  if (t < 128) {
    red[t * 4 + 0] = acc.x; red[t * 4 + 1] = acc.y;
    red[t * 4 + 2] = acc.z; red[t * 4 + 3] = acc.w;
  }
  __syncthreads();
  if (t >= 128) {
    int c = (t - 128) * 4;
    red[c + 0] += acc.x; red[c + 1] += acc.y;
    red[c + 2] += acc.z; red[c + 3] += acc.w;
  }
  __syncthreads();
  if (t < 128)
    *(float4*)(ws + OFF_KP1 + (size_t)bid * 512 + t * 4) = *(float4*)&red[t * 4];
}

// ---------------- R1: reduce 256 chunk-partials per (n,col) ----------------
__global__ __launch_bounds__(256) void k_red1(const float* __restrict__ src,
                                              float* __restrict__ dst) {
  int bid = blockIdx.x;  // 64: n = bid>>3, colgroup = bid&7
  int n = bid >> 3, cg = bid & 7;
  int t = threadIdx.x;
  int col = cg * 64 + (t & 63);
  int ci = t >> 6;  // 0..3
  const float* base = src + (size_t)n * 256 * 512 + col;
  float s = 0.f;
#pragma unroll 8
  for (int c = 0; c < 64; ++c) s += base[(size_t)(ci * 64 + c) * 512];
  __shared__ float red[4][64];
  red[ci][t & 63] = s;
  __syncthreads();
  if (t < 64)
    dst[n * 512 + cg * 64 + t] = red[0][t] + red[1][t] + red[2][t] + red[3][t];
}

// ---------------- P2: fused q-pass partials: qsum AND qn_sum ----------------
__global__ __launch_bounds__(256) void k_qpass(const float* __restrict__ q,
                                               float* __restrict__ ws) {
  int bid = blockIdx.x;  // 2048
  int n = bid >> 8, chunk = bid & 255;
  int t = threadIdx.x;
  int col = (t * 4) & 511;
  __shared__ float vec[512];
  if (t < 128) {
    const float* kp = ws + OFF_KSUM + n * 512 + t * 4;
    vec[t * 4 + 0] = kp[0] + EPSF; vec[t * 4 + 1] = kp[1] + EPSF;
    vec[t * 4 + 2] = kp[2] + EPSF; vec[t * 4 + 3] = kp[3] + EPSF;
  }
  __syncthreads();
  const float4 ve = *(const float4*)&vec[col];
  const float* base = q + (size_t)n * NSTR + (size_t)chunk * 16 * ROWSTR + t * 4;
  float4 qacc = make_float4(0.f, 0.f, 0.f, 0.f);
  float4 nacc = make_float4(0.f, 0.f, 0.f, 0.f);
#pragma unroll
  for (int it = 0; it < 8; ++it) {
    const float4 x = *(const float4*)(base + (size_t)it * 1024);
    float4 s;
    s.x = sigf(x.x); s.y = sigf(x.y); s.z = sigf(x.z); s.w = sigf(x.w);
    qacc.x += s.x; qacc.y += s.y; qacc.z += s.z; qacc.w += s.w;
    float p = (s.x + EPSF) * ve.x + (s.y + EPSF) * ve.y +
              (s.z + EPSF) * ve.z + (s.w + EPSF) * ve.w;
    p = rsum16(p);
    float nrm = 1.0f / p;
    nacc.x += s.x * nrm; nacc.y += s.y * nrm; nacc.z += s.z * nrm; nacc.w += s.w * nrm;
  }
  __shared__ float red[512];
  if (t < 128) {
    red[t * 4 + 0] = qacc.x; red[t * 4 + 1] = qacc.y;
    red[t * 4 + 2] = qacc.z; red[t * 4 + 3] = qacc.w;
  }
  __syncthreads();
  if (t >= 128) {
    int c = (t - 128) * 4;
    red[c + 0] += qacc.x; red[c + 1] += qacc.y;
    red[c + 2] += qacc.z; red[c + 3] += qacc.w;
  }
  __syncthreads();
  if (t < 128)
    *(float4*)(ws + OFF_QP1 + (size_t)bid * 512 + t * 4) = *(float4*)&red[t * 4];
  __syncthreads();
  if (t < 128) {
    red[t * 4 + 0] = nacc.x; red[t * 4 + 1] = nacc.y;
    red[t * 4 + 2] = nacc.z; red[t * 4 + 3] = nacc.w;
  }
  __syncthreads();
  if (t >= 128) {
    int c = (t - 128) * 4;
    red[c + 0] += nacc.x; red[c + 1] += nacc.y;
    red[c + 2] += nacc.z; red[c + 3] += nacc.w;
  }
  __syncthreads();
  if (t < 128)
    *(float4*)(ws + OFF_QNP1 + (size_t)bid * 512 + t * 4) = *(float4*)&red[t * 4];
}

// ---------------- R2: reduce both q partial arrays ----------------
__global__ __launch_bounds__(256) void k_redq(float* __restrict__ ws) {
  int bid = blockIdx.x;  // 128: first 64 -> qsum, next 64 -> qn_sum
  int which = bid >> 6, id = bid & 63;
  const float* src = ws + (which ? OFF_QNP1 : OFF_QP1);
  float* dst = ws + (which ? OFF_QNSUM : OFF_QSUM);
  int n = id >> 3, cg = id & 7;
  int t = threadIdx.x;
  int col = cg * 64 + (t & 63);
  int ci = t >> 6;
  const float* base = src + (size_t)n * 256 * 512 + col;
  float s = 0.f;
#pragma unroll 8
  for (int c = 0; c < 64; ++c) s += base[(size_t)(ci * 64 + c) * 512];
  __shared__ float red[4][64];
  red[ci][t & 63] = s;
  __syncthreads();
  if (t < 64)
    dst[n * 512 + cg * 64 + t] = red[0][t] + red[1][t] + red[2][t] + red[3][t];
}

// ---------------- P3: kv = khat^T v via MFMA, single bf16 (ncraw + kn_sum fused) ----------------
__global__ __launch_bounds__(512, 4) void k_kv(const float* __restrict__ k,
                                               const float* __restrict__ v,
                                               float* __restrict__ ws) {
  const int bid = blockIdx.x;  // 1024
  const int nh = bid >> 4, chunk = bid & 15;
  const int n = nh >> 3, h = nh & 7;
  const int t = threadIdx.x;

  __shared__ unsigned short kt[64][72];
  __shared__ unsigned short vt[64][72];
  __shared__ float knred[8][64];
  __shared__ float zw[8];

  const float* kbase = k + (size_t)n * NSTR + h * DD;
  const float* vbase = v + (size_t)n * NSTR + h * DD;

  const int srow_l = t >> 3;
  const int tq = t & 7;
  const int c0 = tq * 4, c1 = 32 + tq * 4;
  const int s0 = chunk * 256;

  const float* qnp = ws + OFF_QNSUM + nh * 64;
  float4 qa = *(const float4*)(qnp + c0);
  float4 qb = *(const float4*)(qnp + c1);
  qa.x += EPSF; qa.y += EPSF; qa.z += EPSF; qa.w += EPSF;
  qb.x += EPSF; qb.y += EPSF; qb.z += EPSF; qb.w += EPSF;
  const float* qsp = ws + OFF_QSUM + nh * 64;
  float4 sa = *(const float4*)(qsp + c0);
  float4 sb = *(const float4*)(qsp + c1);
  sa.x += EPSF; sa.y += EPSF; sa.z += EPSF; sa.w += EPSF;
  sb.x += EPSF; sb.y += EPSF; sb.z += EPSF; sb.w += EPSF;

  const int w = t >> 6, lane = t & 63;
  const int dblk = w >> 1, ep = w & 1;
  const int m = lane & 15, grp = lane >> 4;
  const int arow = 16 * dblk + m;
  const int brow0 = 16 * (2 * ep) + m;
  const int brow1 = 16 * (2 * ep + 1) + m;

  f32x4 acc0 = {0.f, 0.f, 0.f, 0.f};
  f32x4 acc1 = {0.f, 0.f, 0.f, 0.f};
  float zloc = 0.f;
  float knacc[8];
#pragma unroll
  for (int i = 0; i < 8; ++i) knacc[i] = 0.f;

  const float* krow = kbase + (size_t)(s0 + srow_l) * ROWSTR;
  const float* vrow = vbase + (size_t)(s0 + srow_l) * ROWSTR;
  float4 kA = *(const float4*)(krow + c0);
  float4 kB = *(const float4*)(krow + c1);
  float4 vA = *(const float4*)(vrow + c0);
  float4 vB = *(const float4*)(vrow + c1);

  for (int sub = 0; sub < 4; ++sub) {
    float4 kAn, kBn, vAn, vBn;
    if (sub < 3) {
      const float* krn = kbase + (size_t)(s0 + (sub + 1) * 64 + srow_l) * ROWSTR;
      const float* vrn = vbase + (size_t)(s0 + (sub + 1) * 64 + srow_l) * ROWSTR;
      kAn = *(const float4*)(krn + c0);
      kBn = *(const float4*)(krn + c1);
      vAn = *(const float4*)(vrn + c0);
      vBn = *(const float4*)(vrn + c1);
    }
    float sk[8];
    sk[0] = sigf(kA.x); sk[1] = sigf(kA.y); sk[2] = sigf(kA.z); sk[3] = sigf(kA.w);
    sk[4] = sigf(kB.x); sk[5] = sigf(kB.y); sk[6] = sigf(kB.z); sk[7] = sigf(kB.w);
    float p = (sk[0] + EPSF) * qa.x + (sk[1] + EPSF) * qa.y +
              (sk[2] + EPSF) * qa.z + (sk[3] + EPSF) * qa.w +
              (sk[4] + EPSF) * qb.x + (sk[5] + EPSF) * qb.y +
              (sk[6] + EPSF) * qb.z + (sk[7] + EPSF) * qb.w;
    float p2 = (sk[0] + EPSF) * sa.x + (sk[1] + EPSF) * sa.y +
               (sk[2] + EPSF) * sa.z + (sk[3] + EPSF) * sa.w +
               (sk[4] + EPSF) * sb.x + (sk[5] + EPSF) * sb.y +
               (sk[6] + EPSF) * sb.z + (sk[7] + EPSF) * sb.w;
    p = rsum8(p);
    p2 = rsum8(p2);
    float wgt = __expf(p);
    if (tq == 0) zloc += wgt;
    float inv2 = 1.0f / p2;
#pragma unroll
    for (int i = 0; i < 8; ++i) knacc[i] += sk[i] * inv2;
    float vv[8] = {vA.x, vA.y, vA.z, vA.w, vB.x, vB.y, vB.z, vB.w};
#pragma unroll
    for (int i = 0; i < 8; ++i) {
      int d = (i < 4) ? (c0 + i) : (c1 + i - 4);
      kt[d][srow_l] = b16rne(sk[i] * wgt);
      vt[d][srow_l] = b16rne(vv[i]);
    }
    __syncthreads();
#pragma unroll
    for (int ks = 0; ks < 2; ++ks) {
      const int sb2 = ks * 32 + 8 * grp;
      short8v A  = *(const short8v*)&kt[arow][sb2];
      short8v B0 = *(const short8v*)&vt[brow0][sb2];
      short8v B1 = *(const short8v*)&vt[brow1][sb2];
      acc0 = __builtin_amdgcn_mfma_f32_16x16x32_bf16(A, B0, acc0, 0, 0, 0);
      acc1 = __builtin_amdgcn_mfma_f32_16x16x32_bf16(A, B1, acc1, 0, 0, 0);
    }
    __syncthreads();
    kA = kAn; kB = kBn; vA = vAn; vB = vBn;
  }

  float* dst = ws + OFF_KVP + (size_t)bid * 4096;
  const int drow = 16 * dblk + 4 * grp;
#pragma unroll
  for (int r = 0; r < 4; ++r) {
    dst[(drow + r) * 64 + brow0] = acc0[r];
    dst[(drow + r) * 64 + brow1] = acc1[r];
  }

  // kn partials: fold lanes sharing tq (xor 8/16/32), then across waves in LDS
#pragma unroll
  for (int i = 0; i < 8; ++i) {
    knacc[i] += __shfl_xor(knacc[i], 8, 64);
    knacc[i] += __shfl_xor(knacc[i], 16, 64);
    knacc[i] += __shfl_xor(knacc[i], 32, 64);
  }
  if (lane < 8) {
#pragma unroll
    for (int i = 0; i < 4; ++i) {
      knred[w][lane * 4 + i] = knacc[i];
      knred[w][32 + lane * 4 + i] = knacc[4 + i];
    }
  }
  // z partial: shfl fold within wave (zloc lives on tq==0 lanes)
  zloc += __shfl_xor(zloc, 8, 64);
  zloc += __shfl_xor(zloc, 16, 64);
  zloc += __shfl_xor(zloc, 32, 64);
  if (lane == 0) zw[w] = zloc;
  __syncthreads();
  if (t < 64) {
    float s = 0.f;
#pragma unroll
    for (int ww = 0; ww < 8; ++ww) s += knred[ww][t];
    ws[OFF_KNP + (size_t)bid * 64 + t] = s;
  }
  if (t == 0) {
    float s = 0.f;
#pragma unroll
    for (int ww = 0; ww < 8; ++ww) s += zw[ww];
    ws[OFF_ZP + bid] = s;
  }
}

// ---------------- P4: reduce partials (kv, kn, z), apply S/Z, transpose, emit bf16 kv^T ----------------
__global__ __launch_bounds__(256) void k_kvred(float* __restrict__ ws) {
  int nh = blockIdx.x;  // 64
  int t = threadIdx.x;
  // Z from partials
  const float* zp = ws + OFF_ZP;
  float z = 0.f;
#pragma unroll
  for (int c = 0; c < 16; ++c) z += zp[nh * 16 + c];
  float scale = (float)LL / z;
  // kn_sum from partials
  if (t < 64) {
    const float* knp = ws + OFF_KNP;
    float s = 0.f;
#pragma unroll
    for (int c = 0; c < 16; ++c) s += knp[(size_t)(nh * 16 + c) * 64 + t];
    ws[OFF_KNSUM + nh * 64 + t] = s;
  }
  __shared__ float lds[64][69];
  const float4* src = (const float4*)(ws + OFF_KVP);
#pragma unroll
  for (int i = 0; i < 4; ++i) {
    int off = i * 256 + t;
    float4 s = make_float4(0.f, 0.f, 0.f, 0.f);
#pragma unroll
    for (int c = 0; c < 16; ++c) {
      float4 x = src[(size_t)((nh * 16 + c) << 10) + off];
      s.x += x.x; s.y += x.y; s.z += x.z; s.w += x.w;
    }
    int d = off >> 4, e0 = (off & 15) * 4;
    lds[d][e0 + 0] = s.x * scale; lds[d][e0 + 1] = s.y * scale;
    lds[d][e0 + 2] = s.z * scale; lds[d][e0 + 3] = s.w * scale;
  }
  __syncthreads();
  int e = t >> 2, d0 = (t & 3) * 16;
  unsigned int words[8];
#pragma unroll
  for (int j = 0; j < 8; ++j)
    words[j] = pack2(lds[d0 + 2 * j][e], lds[d0 + 2 * j + 1][e]);
  unsigned int* dstp = (unsigned int*)((unsigned short*)(ws + OFF_KV) + (size_t)nh * 4096 + e * 64 + d0);
#pragma unroll
  for (int j = 0; j < 8; ++j) dstp[j] = words[j];
}

// ---------------- P5: out = (sig(q) . kv) * scl via MFMA ----------------
__global__ __launch_bounds__(256) void k_out(const float* __restrict__ q,
                                             float* __restrict__ out,
                                             const float* __restrict__ ws) {
  int bid = blockIdx.x;  // 2048
  int nh = bid >> 5, chunk = bid & 31;
  int n = nh >> 3, h = nh & 7;
  int t = threadIdx.x, tq = t & 15, g = t >> 4;
  __shared__ unsigned short sqb[128][72];
  __shared__ unsigned short kvb[64][72];
  __shared__ float scl[128];
  __shared__ float ksv[64], knv[64];
  if (t < 64) {
    ksv[t] = ws[OFF_KSUM + nh * 64 + t] + EPSF;
    knv[t] = ws[OFF_KNSUM + nh * 64 + t] + EPSF;
  }
  {
    int r0 = t >> 2, c0 = (t & 3) * 16;
    const short8v* gsrc = (const short8v*)((const unsigned short*)(ws + OFF_KV) +
                                           (size_t)nh * 4096 + r0 * 64 + c0);
    short8v a = gsrc[0], b = gsrc[1];
    *(short8v*)&kvb[r0][c0] = a;
    *(short8v*)&kvb[r0][c0 + 8] = b;
  }
  __syncthreads();
  const float4 ke = *(const float4*)&ksv[tq * 4];
  const float4 kne = *(const float4*)&knv[tq * 4];
  const float* qbase = q + (size_t)n * NSTR + h * DD + tq * 4;
  int l0 = chunk * 128;
#pragma unroll
  for (int rr = 0; rr < 8; ++rr) {
    int row = g + rr * 16;
    const float4 x = *(const float4*)(qbase + (size_t)(l0 + row) * ROWSTR);
    float4 s;
    s.x = sigf(x.x); s.y = sigf(x.y); s.z = sigf(x.z); s.w = sigf(x.w);
    *(unsigned int*)&sqb[row][tq * 4] = pack2(s.x, s.y);
    *(unsigned int*)&sqb[row][tq * 4 + 2] = pack2(s.z, s.w);
    float p1 = (s.x + EPSF) * ke.x + (s.y + EPSF) * ke.y +
               (s.z + EPSF) * ke.z + (s.w + EPSF) * ke.w;
    float p2 = (s.x + EPSF) * kne.x + (s.y + EPSF) * kne.y +
               (s.z + EPSF) * kne.z + (s.w + EPSF) * kne.w;
    p1 = rsum16(p1);
    p2 = rsum16(p2);
    if (tq == 0) scl[row] = (1.0f / p1) * sigf(p2);  // L/S == 1
  }
  __syncthreads();
  int w = t >> 6, lane = t & 63;
  int m = lane & 15, grp = lane >> 4;
  f32x4 a00 = {0,0,0,0}, a01 = {0,0,0,0}, a02 = {0,0,0,0}, a03 = {0,0,0,0};
  f32x4 a10 = {0,0,0,0}, a11 = {0,0,0,0}, a12 = {0,0,0,0}, a13 = {0,0,0,0};
#pragma unroll
  for (int ks = 0; ks < 2; ++ks) {
    const int sb = ks * 32 + 8 * grp;
    short8v A0 = *(const short8v*)&sqb[(2 * w + 0) * 16 + m][sb];
    short8v A1 = *(const short8v*)&sqb[(2 * w + 1) * 16 + m][sb];
    short8v B0 = *(const short8v*)&kvb[0 * 16 + m][sb];
    short8v B1 = *(const short8v*)&kvb[1 * 16 + m][sb];
    short8v B2 = *(const short8v*)&kvb[2 * 16 + m][sb];
    short8v B3 = *(const short8v*)&kvb[3 * 16 + m][sb];
    a00 = __builtin_amdgcn_mfma_f32_16x16x32_bf16(A0, B0, a00, 0, 0, 0);
    a01 = __builtin_amdgcn_mfma_f32_16x16x32_bf16(A0, B1, a01, 0, 0, 0);
    a02 = __builtin_amdgcn_mfma_f32_16x16x32_bf16(A0, B2, a02, 0, 0, 0);
    a03 = __builtin_amdgcn_mfma_f32_16x16x32_bf16(A0, B3, a03, 0, 0, 0);
    a10 = __builtin_amdgcn_mfma_f32_16x16x32_bf16(A1, B0, a10, 0, 0, 0);
    a11 = __builtin_amdgcn_mfma_f32_16x16x32_bf16(A1, B1, a11, 0, 0, 0);
    a12 = __builtin_amdgcn_mfma_f32_16x16x32_bf16(A1, B2, a12, 0, 0, 0);
    a13 = __builtin_amdgcn_mfma_f32_16x16x32_bf16(A1, B3, a13, 0, 0, 0);
  }
  float* obase = out + (size_t)n * NSTR + h * DD;
#pragma unroll
  for (int mt = 0; mt < 2; ++mt) {
    int lrow = (2 * w + mt) * 16 + 4 * grp;
#pragma unroll
    for (int r = 0; r < 4; ++r) {
      float sc = scl[lrow + r];
      float* orow = obase + (size_t)(l0 + lrow + r) * ROWSTR;
      if (mt == 0) {
        orow[0 * 16 + m] = a00[r] * sc; orow[1 * 16 + m] = a01[r] * sc;
        orow[2 * 16 + m] = a02[r] * sc; orow[3 * 16 + m] = a03[r] * sc;
      } else {
        orow[0 * 16 + m] = a10[r] * sc; orow[1 * 16 + m] = a11[r] * sc;
        orow[2 * 16 + m] = a12[r] * sc; orow[3 * 16 + m] = a13[r] * sc;
      }
    }
  }
}

extern "C" void kernel_launch(void* const* d_in, const int* in_sizes, int n_in,
                              void* d_out, int out_size, void* d_ws, size_t ws_size,
                              hipStream_t stream) {
  const float* q = (const float*)d_in[0];
  const float* k = (const float*)d_in[1];
  const float* v = (const float*)d_in[2];
  float* out = (float*)d_out;
  float* ws = (float*)d_ws;

  // no memset: every ws region is fully overwritten before it is read
  hipLaunchKernelGGL(k_ksum, dim3(2048), dim3(256), 0, stream, k, ws);
  hipLaunchKernelGGL(k_red1, dim3(64), dim3(256), 0, stream, ws + OFF_KP1, ws + OFF_KSUM);
  hipLaunchKernelGGL(k_qpass, dim3(2048), dim3(256), 0, stream, q, ws);
  hipLaunchKernelGGL(k_redq, dim3(128), dim3(256), 0, stream, ws);
  hipLaunchKernelGGL(k_kv, dim3(1024), dim3(512), 0, stream, k, v, ws);
  hipLaunchKernelGGL(k_kvred, dim3(64), dim3(256), 0, stream, ws);
  hipLaunchKernelGGL(k_out, dim3(2048), dim3(256), 0, stream, q, out, ws);
}